// Round 1
// baseline (560.139 us; speedup 1.0000x reference)
//
#include <hip/hip_runtime.h>
#include <math.h>

#define QSEQ 33600
#define DM 256
#define NHEADS 8

// ---------------------------------------------------------------------------
// GEMM: C[M,N] = (A [+ A2]) @ W^T + bias;  A:[M,256] row-major, W:[N,256] row-major
// Tiling: BM=64, BN=64, BK=16, 256 threads, each computes 4x4.
// M is always 33600 (divisible by 64), K=256 (divisible by 16). N guarded.
// ---------------------------------------------------------------------------
__global__ __launch_bounds__(256) void gemm_bias_kernel(
    const float* __restrict__ A, const float* __restrict__ A2,
    const float* __restrict__ W, const float* __restrict__ bias,
    float* __restrict__ C, int N) {
  constexpr int BM = 64, BN = 64, BK = 16, TM = 4, TN = 4, K = 256;
  __shared__ float As[BK][BM + 4];
  __shared__ float Bs[BK][BN + 4];
  const int tid = threadIdx.x;
  const int bm = blockIdx.y * BM;
  const int bn = blockIdx.x * BN;
  const int tx = tid & 15;        // 16 cols of threads
  const int ty = tid >> 4;        // 16 rows of threads
  const int lrow = tid >> 2;      // 0..63 : tile row for loads
  const int lk4 = (tid & 3) * 4;  // 0,4,8,12 : k sub-offset for loads

  float acc[TM][TN] = {};

  for (int k0 = 0; k0 < K; k0 += BK) {
    // --- A tile (with optional fused add) ---
    float4 a4 = *(const float4*)(&A[(size_t)(bm + lrow) * K + k0 + lk4]);
    if (A2) {
      const float4 a2 = *(const float4*)(&A2[(size_t)(bm + lrow) * K + k0 + lk4]);
      a4.x += a2.x; a4.y += a2.y; a4.z += a2.z; a4.w += a2.w;
    }
    As[lk4 + 0][lrow] = a4.x;
    As[lk4 + 1][lrow] = a4.y;
    As[lk4 + 2][lrow] = a4.z;
    As[lk4 + 3][lrow] = a4.w;
    // --- B tile: Bs[k][n] = W[bn+n][k0+k] ---
    float4 b4 = make_float4(0.f, 0.f, 0.f, 0.f);
    if (bn + lrow < N)
      b4 = *(const float4*)(&W[(size_t)(bn + lrow) * K + k0 + lk4]);
    Bs[lk4 + 0][lrow] = b4.x;
    Bs[lk4 + 1][lrow] = b4.y;
    Bs[lk4 + 2][lrow] = b4.z;
    Bs[lk4 + 3][lrow] = b4.w;
    __syncthreads();

#pragma unroll
    for (int k = 0; k < BK; ++k) {
      float a[TM], b[TN];
#pragma unroll
      for (int i = 0; i < TM; ++i) a[i] = As[k][ty * TM + i];
#pragma unroll
      for (int j = 0; j < TN; ++j) b[j] = Bs[k][tx * TN + j];
#pragma unroll
      for (int i = 0; i < TM; ++i)
#pragma unroll
        for (int j = 0; j < TN; ++j)
          acc[i][j] = fmaf(a[i], b[j], acc[i][j]);
    }
    __syncthreads();
  }

  // epilogue: add bias, vectorized store (N is a multiple of 4)
  const int n0 = bn + tx * TN;
  if (n0 < N) {
    float4 bia = *(const float4*)(&bias[n0]);
#pragma unroll
    for (int i = 0; i < TM; ++i) {
      const int m = bm + ty * TM + i;
      float4 v;
      v.x = acc[i][0] + bia.x;
      v.y = acc[i][1] + bia.y;
      v.z = acc[i][2] + bia.z;
      v.w = acc[i][3] + bia.w;
      *(float4*)(&C[(size_t)m * N + n0]) = v;
    }
  }
}

// ---------------------------------------------------------------------------
// In-place softmax over groups of 12 (one thread per (q, head)).
// ---------------------------------------------------------------------------
__global__ __launch_bounds__(256) void softmax12_kernel(float* __restrict__ x, int count) {
  const int t = blockIdx.x * blockDim.x + threadIdx.x;
  if (t >= count) return;
  float* p = x + (size_t)t * 12;
  float v[12];
  float m = -1e30f;
#pragma unroll
  for (int i = 0; i < 12; ++i) { v[i] = p[i]; m = fmaxf(m, v[i]); }
  float s = 0.f;
#pragma unroll
  for (int i = 0; i < 12; ++i) { v[i] = expf(v[i] - m); s += v[i]; }
  const float inv = 1.f / s;
#pragma unroll
  for (int i = 0; i < 12; ++i) p[i] = v[i] * inv;
}

// ---------------------------------------------------------------------------
// Sampling + aggregation. One wave (64 lanes) per (q, head).
// lane = ph*32 + c : ph in {0,1} picks one of 2 points per iteration,
// c in [0,32) is the head channel. 6 iterations cover 12 points.
// pixel_x = rp_x * W + off_x - 0.5 (grid_sample align_corners=False collapse).
// ---------------------------------------------------------------------------
__global__ __launch_bounds__(256) void msda_sample_kernel(
    const float* __restrict__ value,   // [Q, 256]
    const float* __restrict__ sp,      // [Q, 192] raw offsets
    const float* __restrict__ attn,    // [Q, 96]  softmaxed
    const float* __restrict__ refp,    // [Q, 3, 2]
    float* __restrict__ outp) {        // [Q, 256] pre-projection
  const int gwave = (blockIdx.x * 256 + threadIdx.x) >> 6;
  const int lane = threadIdx.x & 63;
  const int q = gwave >> 3;
  const int h = gwave & 7;
  const int ph = lane >> 5;
  const int c = lane & 31;

  const int lsz[3] = {160, 80, 40};
  const int lst[3] = {0, 25600, 32000};

  float acc = 0.f;
#pragma unroll
  for (int it = 0; it < 6; ++it) {
    const int pt = it * 2 + ph;       // 0..11
    const int lvl = pt >> 2;
    const float a  = attn[(size_t)q * 96 + h * 12 + pt];
    const float ox = sp[(size_t)q * 192 + h * 24 + pt * 2 + 0];
    const float oy = sp[(size_t)q * 192 + h * 24 + pt * 2 + 1];
    const float rx = refp[(size_t)q * 6 + lvl * 2 + 0];
    const float ry = refp[(size_t)q * 6 + lvl * 2 + 1];
    const int S = lsz[lvl];
    const int base = lst[lvl];

    const float x = rx * (float)S + ox - 0.5f;
    const float y = ry * (float)S + oy - 0.5f;
    const float xf = floorf(x), yf = floorf(y);
    const int x0 = (int)xf, y0 = (int)yf;
    const float wx1 = x - xf, wy1 = y - yf;
    const float wx0 = 1.f - wx1, wy0 = 1.f - wy1;

    const bool xv0 = (x0 >= 0) & (x0 < S);
    const bool xv1 = (x0 + 1 >= 0) & (x0 + 1 < S);
    const bool yv0 = (y0 >= 0) & (y0 < S);
    const bool yv1 = (y0 + 1 >= 0) & (y0 + 1 < S);

    float v00 = 0.f, v10 = 0.f, v01 = 0.f, v11 = 0.f;
    if (yv0) {
      const float* row = value + ((size_t)(base + y0 * S)) * 256 + h * 32 + c;
      if (xv0) v00 = row[(size_t)x0 * 256];
      if (xv1) v10 = row[(size_t)(x0 + 1) * 256];
    }
    if (yv1) {
      const float* row = value + ((size_t)(base + (y0 + 1) * S)) * 256 + h * 32 + c;
      if (xv0) v01 = row[(size_t)x0 * 256];
      if (xv1) v11 = row[(size_t)(x0 + 1) * 256];
    }
    acc += a * (v00 * wx0 * wy0 + v10 * wx1 * wy0 + v01 * wx0 * wy1 + v11 * wx1 * wy1);
  }
  // combine the two point-halves (lane c and lane c+32 hold partials for channel c)
  acc += __shfl_down(acc, 32, 64);
  if (ph == 0) outp[(size_t)q * 256 + h * 32 + c] = acc;
}

extern "C" void kernel_launch(void* const* d_in, const int* in_sizes, int n_in,
                              void* d_out, int out_size, void* d_ws, size_t ws_size,
                              hipStream_t stream) {
  const float* hidden = (const float*)d_in[0];
  const float* ehs    = (const float*)d_in[1];
  const float* pos    = (const float*)d_in[2];
  const float* refp   = (const float*)d_in[3];
  const float* Wv = (const float*)d_in[4];
  const float* bv = (const float*)d_in[5];
  const float* Ws = (const float*)d_in[6];
  const float* bs = (const float*)d_in[7];
  const float* Wa = (const float*)d_in[8];
  const float* ba = (const float*)d_in[9];
  const float* Wo = (const float*)d_in[10];
  const float* bo = (const float*)d_in[11];

  float* out  = (float*)d_out;                   // [Q, 256]
  float* attn = out + (size_t)QSEQ * 256;        // [Q, 96]

  float* wsf = (float*)d_ws;
  float* ws_value = wsf;                               // Q*256
  float* ws_sp    = ws_value + (size_t)QSEQ * 256;     // Q*192
  float* ws_out   = ws_sp    + (size_t)QSEQ * 192;     // Q*256

  dim3 blk(256);

  // 1. value = ehs @ Wv^T + bv
  gemm_bias_kernel<<<dim3(4, 525), blk, 0, stream>>>(ehs, nullptr, Wv, bv, ws_value, 256);
  // 2. raw sampling offsets = (hidden+pos) @ Ws^T + bs
  gemm_bias_kernel<<<dim3(3, 525), blk, 0, stream>>>(hidden, pos, Ws, bs, ws_sp, 192);
  // 3. attn logits = (hidden+pos) @ Wa^T + ba  -> directly into d_out attn region
  gemm_bias_kernel<<<dim3(2, 525), blk, 0, stream>>>(hidden, pos, Wa, ba, attn, 96);
  // 4. softmax over 12 points, in place
  softmax12_kernel<<<dim3((QSEQ * NHEADS + 255) / 256), blk, 0, stream>>>(attn, QSEQ * NHEADS);
  // 5. bilinear sampling + attention-weighted aggregation
  msda_sample_kernel<<<dim3(QSEQ * NHEADS / 4), blk, 0, stream>>>(ws_value, ws_sp, attn, refp, ws_out);
  // 6. output = ws_out @ Wo^T + bo
  gemm_bias_kernel<<<dim3(4, 525), blk, 0, stream>>>(ws_out, nullptr, Wo, bo, out, 256);
}